// Round 1
// baseline (97.902 us; speedup 1.0000x reference)
//
#include <hip/hip_runtime.h>

// ---------------- workspace layout (floats) ----------------
// acc      : 1      @ 0
// gt2      : 4*3*36*36 = 15552 @ 16
// gt4      : 4*3*18*18 = 3888  @ 16+15552
// p1       : 4*576*9  = 20736  @ ...
// p2cat    : 4*756*9  = 27216  @ ...
#define ACC_OFF   0
#define GT2_OFF   16
#define GT4_OFF   (GT2_OFF + 15552)
#define P1_OFF    (GT4_OFF + 3888)
#define P2CAT_OFF (P1_OFF + 20736)

__device__ __forceinline__ int clip71(int v) { return v < 0 ? 0 : (v > 71 ? 71 : v); }

// ---------------- kernel A: bicubic downsample gt -> gt2 (f=2), gt4 (f=4) ----
// torch bicubic a=-0.75, align_corners=False, integer factor => fixed weights.
// Reference order: H-axis first, then W-axis, sequential k accumulation.
__global__ void ds_kernel(const float* __restrict__ gt, float* __restrict__ ws) {
    const float W0 = -0.09375f, W1 = 0.59375f, W2 = 0.59375f, W3 = -0.09375f;
    int tid = blockIdx.x * blockDim.x + threadIdx.x;
    if (tid == 0) ws[ACC_OFF] = 0.0f;   // zero L1 accumulator every call (ws is poisoned)
    if (tid < 15552) {
        // f=2: out 36x36. taps r = 2*oh-1+k (clip), cols likewise.
        int ow = tid % 36; int t = tid / 36; int oh = t % 36; int bc = t / 36; // bc in [0,12)
        const float* src = gt + bc * 5184;
        int r0 = clip71(2*oh - 1), r1 = 2*oh, r2 = 2*oh + 1, r3 = clip71(2*oh + 2);
        int c0 = clip71(2*ow - 1), c1 = 2*ow, c2 = 2*ow + 1, c3 = clip71(2*ow + 2);
        float t0, t1, t2, t3, o;
        t0  = W0 * src[r0*72 + c0]; t0 += W1 * src[r1*72 + c0]; t0 += W2 * src[r2*72 + c0]; t0 += W3 * src[r3*72 + c0];
        t1  = W0 * src[r0*72 + c1]; t1 += W1 * src[r1*72 + c1]; t1 += W2 * src[r2*72 + c1]; t1 += W3 * src[r3*72 + c1];
        t2  = W0 * src[r0*72 + c2]; t2 += W1 * src[r1*72 + c2]; t2 += W2 * src[r2*72 + c2]; t2 += W3 * src[r3*72 + c2];
        t3  = W0 * src[r0*72 + c3]; t3 += W1 * src[r1*72 + c3]; t3 += W2 * src[r2*72 + c3]; t3 += W3 * src[r3*72 + c3];
        o  = W0 * t0; o += W1 * t1; o += W2 * t2; o += W3 * t3;
        ws[GT2_OFF + tid] = o;
    } else if (tid < 19440) {
        // f=4: out 18x18. taps r = 4*oh+k, never out of range (4*17+3 = 71).
        int u = tid - 15552;
        int ow = u % 18; int t = u / 18; int oh = t % 18; int bc = t / 18;
        const float* src = gt + bc * 5184;
        int r0 = 4*oh, r1 = 4*oh + 1, r2 = 4*oh + 2, r3 = 4*oh + 3;
        int c0 = 4*ow, c1 = 4*ow + 1, c2 = 4*ow + 2, c3 = 4*ow + 3;
        float t0, t1, t2, t3, o;
        t0  = W0 * src[r0*72 + c0]; t0 += W1 * src[r1*72 + c0]; t0 += W2 * src[r2*72 + c0]; t0 += W3 * src[r3*72 + c0];
        t1  = W0 * src[r0*72 + c1]; t1 += W1 * src[r1*72 + c1]; t1 += W2 * src[r2*72 + c1]; t1 += W3 * src[r3*72 + c1];
        t2  = W0 * src[r0*72 + c2]; t2 += W1 * src[r1*72 + c2]; t2 += W2 * src[r2*72 + c2]; t2 += W3 * src[r3*72 + c2];
        t3  = W0 * src[r0*72 + c3]; t3 += W1 * src[r1*72 + c3]; t3 += W2 * src[r2*72 + c3]; t3 += W3 * src[r3*72 + c3];
        o  = W0 * t0; o += W1 * t1; o += W2 * t2; o += W3 * t3;
        ws[GT4_OFF + u] = o;
    }
}

// ---------------- kernel B: patch grams for x, gt, gt2, gt4 ------------------
// Each thread: one 3x3 patch. Features [3 channels][9 pixels]; gram[c][d] =
// sum_e pix[c][e]*pix[d][e] / 27 (sequential e, true division to match ref).
// Symmetric halves written from one dot (bitwise-equal, as einsum produces).
__global__ void gram_kernel(const float* __restrict__ x, const float* __restrict__ gt,
                            float* __restrict__ ws) {
    int tid = blockIdx.x * blockDim.x + threadIdx.x;
    if (tid >= 5328) return;
    const float* img; int Wd, PW; float* dst; int b, n;
    if (tid < 2304) {                 // p1 from x (72x72, 576 patches/batch)
        b = tid / 576; n = tid - b*576;
        img = x + b*15552; Wd = 72; PW = 24;
        dst = ws + P1_OFF + tid*9;
    } else if (tid < 4608) {          // p2 from gt -> p2cat rows [0,576)
        int t = tid - 2304; b = t / 576; n = t - b*576;
        img = gt + b*15552; Wd = 72; PW = 24;
        dst = ws + P2CAT_OFF + (b*756 + n)*9;
    } else if (tid < 5184) {          // from gt2 (36x36, 144/batch) -> rows [576,720)
        int t = tid - 4608; b = t / 144; n = t - b*144;
        img = ws + GT2_OFF + b*3888; Wd = 36; PW = 12;
        dst = ws + P2CAT_OFF + (b*756 + 576 + n)*9;
    } else {                          // from gt4 (18x18, 36/batch) -> rows [720,756)
        int t = tid - 5184; b = t / 36; n = t - b*36;
        img = ws + GT4_OFF + b*972; Wd = 18; PW = 6;
        dst = ws + P2CAT_OFF + (b*756 + 720 + n)*9;
    }
    int ph = n / PW, pw = n - ph*PW;
    int hw = Wd * Wd;
    const float* base = img + (3*ph)*Wd + 3*pw;
    float pix[3][9];
    #pragma unroll
    for (int c = 0; c < 3; ++c)
        #pragma unroll
        for (int i = 0; i < 3; ++i)
            #pragma unroll
            for (int j = 0; j < 3; ++j)
                pix[c][i*3 + j] = base[c*hw + i*Wd + j];
    #pragma unroll
    for (int c = 0; c < 3; ++c)
        #pragma unroll
        for (int d = c; d < 3; ++d) {
            float g = 0.0f;
            #pragma unroll
            for (int e = 0; e < 9; ++e) g += pix[c][e] * pix[d][e];
            g = g / 27.0f;
            dst[c*3 + d] = g;
            dst[d*3 + c] = g;
        }
}

// ---------------- kernel C: score + argmin + L1 partial sum ------------------
// One 64-lane wave per (b,n); lanes split m over [0,756) stride 64.
// score(m) = max(n1+nq-2*p1.q, 0) + max(n2+nq-2*p2.q, 0); first-min tie-break.
__global__ void __launch_bounds__(256)
score_kernel(const float* __restrict__ ws_ro, float* __restrict__ ws) {
    const float* p1c  = ws_ro + P1_OFF;
    const float* p2c  = ws_ro + P2CAT_OFF;
    int wave = blockIdx.x * 4 + (threadIdx.x >> 6);   // 576 blocks * 4 waves = 2304
    int lane = threadIdx.x & 63;
    int b = wave / 576, n = wave - b*576;
    const float* a1 = p1c + (b*576 + n)*9;
    const float* a2 = p2c + (b*756 + n)*9;            // p2 row n sits at p2cat[n]
    float v1[9], v2[9];
    #pragma unroll
    for (int d = 0; d < 9; ++d) { v1[d] = a1[d]; v2[d] = a2[d]; }
    float n1 = 0.0f, n2 = 0.0f;
    #pragma unroll
    for (int d = 0; d < 9; ++d) { n1 += v1[d]*v1[d]; n2 += v2[d]*v2[d]; }
    float best = 3.402823466e+38f;
    int bidx = 0x7fffffff;
    const float* qb = p2c + b*756*9;
    for (int m = lane; m < 756; m += 64) {
        const float* q = qb + m*9;
        float nq = 0.0f, d1 = 0.0f, d2 = 0.0f;
        #pragma unroll
        for (int d = 0; d < 9; ++d) {
            float qv = q[d];
            nq += qv*qv; d1 += v1[d]*qv; d2 += v2[d]*qv;
        }
        float s = fmaxf((n1 + nq) - 2.0f*d1, 0.0f) + fmaxf((n2 + nq) - 2.0f*d2, 0.0f);
        if (s < best) { best = s; bidx = m; }         // strict <: first-min within lane
    }
    // cross-lane argmin, ties -> smaller index (matches jnp.argmin first-occurrence)
    #pragma unroll
    for (int off = 32; off > 0; off >>= 1) {
        float ob = __shfl_down(best, off);
        int   oi = __shfl_down(bidx, off);
        if (ob < best || (ob == best && oi < bidx)) { best = ob; bidx = oi; }
    }
    if (lane == 0) {
        const float* q = qb + bidx*9;
        float s = 0.0f;
        #pragma unroll
        for (int d = 0; d < 9; ++d) s += fabsf(v1[d] - q[d]);
        atomicAdd(ws + ACC_OFF, s);
    }
}

// ---------------- kernel D: finalize ----------------------------------------
__global__ void finalize_kernel(const float* __restrict__ ws, float* __restrict__ out) {
    if (threadIdx.x == 0 && blockIdx.x == 0)
        out[0] = ws[ACC_OFF] / 20736.0f;              // mean over 4*576*9
}

extern "C" void kernel_launch(void* const* d_in, const int* in_sizes, int n_in,
                              void* d_out, int out_size, void* d_ws, size_t ws_size,
                              hipStream_t stream) {
    const float* x  = (const float*)d_in[0];
    const float* gt = (const float*)d_in[1];
    float* ws  = (float*)d_ws;
    float* out = (float*)d_out;

    ds_kernel<<<76, 256, 0, stream>>>(gt, ws);             // 19440 threads
    gram_kernel<<<21, 256, 0, stream>>>(x, gt, ws);        // 5328 threads
    score_kernel<<<576, 256, 0, stream>>>(ws, ws);         // 2304 waves
    finalize_kernel<<<1, 64, 0, stream>>>(ws, out);
}

// Round 2
// 92.417 us; speedup vs baseline: 1.0594x; 1.0594x over previous
//
#include <hip/hip_runtime.h>

// ---------------- workspace layout (floats) ----------------
#define PART_OFF  0                     // 576 per-block partial L1 sums
#define P1_OFF    1024                  // 4*576*9  = 20736
#define P2CAT_OFF (P1_OFF + 20736)     // 4*756*9  = 27216

__device__ __forceinline__ int clip71(int v) { return v < 0 ? 0 : (v > 71 ? 71 : v); }

#define W0 (-0.09375f)
#define W1 (0.59375f)
#define W2 (0.59375f)
#define W3 (-0.09375f)

// ---------------- kernel 1: fused downsample + patch grams -------------------
// tid < 2304 : p1 grams from x          (72x72, 576 patches/batch)
// tid < 4608 : p2 grams from gt  -> p2cat rows [0,576)
// tid < 5184 : grams of bicubic f=2(gt) -> rows [576,720)  (downsample inline)
// tid < 5328 : grams of bicubic f=4(gt) -> rows [720,756)  (downsample inline)
// Branch boundaries are multiples of 64 -> wave-uniform divergence.
__global__ void fused_gram_kernel(const float* __restrict__ x, const float* __restrict__ gt,
                                  float* __restrict__ ws) {
    int tid = blockIdx.x * blockDim.x + threadIdx.x;
    if (tid >= 5328) return;

    float pix[3][9];
    float* dst;

    if (tid < 4608) {
        // direct 3x3 patches of a 72x72 image (x or gt)
        const float* img; int b, n;
        if (tid < 2304) {
            b = tid / 576; n = tid - b*576;
            img = x + b*15552;
            dst = ws + P1_OFF + tid*9;
        } else {
            int t = tid - 2304; b = t / 576; n = t - b*576;
            img = gt + b*15552;
            dst = ws + P2CAT_OFF + (b*756 + n)*9;
        }
        int ph = n / 24, pw = n - ph*24;
        const float* base = img + (3*ph)*72 + 3*pw;
        #pragma unroll
        for (int c = 0; c < 3; ++c)
            #pragma unroll
            for (int i = 0; i < 3; ++i)
                #pragma unroll
                for (int j = 0; j < 3; ++j)
                    pix[c][i*3 + j] = base[c*5184 + i*72 + j];
    } else if (tid < 5184) {
        // f=2 bicubic downsample of gt computed inline (8x8 source window),
        // fp order identical to reference: H-pass (sequential k) then W-pass.
        int t = tid - 4608; int b = t / 144; int n = t - b*144;
        int ph = n / 12, pw = n - ph*12;
        dst = ws + P2CAT_OFF + (b*756 + 576 + n)*9;
        int rt[8], ct[8];
        #pragma unroll
        for (int k = 0; k < 8; ++k) {
            rt[k] = clip71(6*ph - 1 + k);
            ct[k] = clip71(6*pw - 1 + k);
        }
        #pragma unroll
        for (int c = 0; c < 3; ++c) {
            const float* src = gt + (b*3 + c)*5184;
            float R[8][8];
            #pragma unroll
            for (int i = 0; i < 8; ++i)
                #pragma unroll
                for (int j = 0; j < 8; ++j)
                    R[i][j] = src[rt[i]*72 + ct[j]];
            #pragma unroll
            for (int i = 0; i < 3; ++i)
                #pragma unroll
                for (int j = 0; j < 3; ++j) {
                    float t0, t1, t2, t3, o;
                    t0  = W0 * R[2*i][2*j];   t0 += W1 * R[2*i+1][2*j];   t0 += W2 * R[2*i+2][2*j];   t0 += W3 * R[2*i+3][2*j];
                    t1  = W0 * R[2*i][2*j+1]; t1 += W1 * R[2*i+1][2*j+1]; t1 += W2 * R[2*i+2][2*j+1]; t1 += W3 * R[2*i+3][2*j+1];
                    t2  = W0 * R[2*i][2*j+2]; t2 += W1 * R[2*i+1][2*j+2]; t2 += W2 * R[2*i+2][2*j+2]; t2 += W3 * R[2*i+3][2*j+2];
                    t3  = W0 * R[2*i][2*j+3]; t3 += W1 * R[2*i+1][2*j+3]; t3 += W2 * R[2*i+2][2*j+3]; t3 += W3 * R[2*i+3][2*j+3];
                    o  = W0 * t0; o += W1 * t1; o += W2 * t2; o += W3 * t3;
                    pix[c][i*3 + j] = o;
                }
        }
    } else {
        // f=4 bicubic downsample of gt computed inline (taps never clip:
        // rows 12*ph+4i+k <= 71). Per-pixel 4x4 tap window.
        int t = tid - 5184; int b = t / 36; int n = t - b*36;
        int ph = n / 6, pw = n - ph*6;
        dst = ws + P2CAT_OFF + (b*756 + 720 + n)*9;
        #pragma unroll
        for (int c = 0; c < 3; ++c) {
            const float* src = gt + (b*3 + c)*5184;
            #pragma unroll
            for (int i = 0; i < 3; ++i)
                #pragma unroll
                for (int j = 0; j < 3; ++j) {
                    const float* p = src + (12*ph + 4*i)*72 + (12*pw + 4*j);
                    float t0, t1, t2, t3, o;
                    t0  = W0 * p[0];      t0 += W1 * p[72];     t0 += W2 * p[144];    t0 += W3 * p[216];
                    t1  = W0 * p[1];      t1 += W1 * p[73];     t1 += W2 * p[145];    t1 += W3 * p[217];
                    t2  = W0 * p[2];      t2 += W1 * p[74];     t2 += W2 * p[146];    t2 += W3 * p[218];
                    t3  = W0 * p[3];      t3 += W1 * p[75];     t3 += W2 * p[147];    t3 += W3 * p[219];
                    o  = W0 * t0; o += W1 * t1; o += W2 * t2; o += W3 * t3;
                    pix[c][i*3 + j] = o;
                }
        }
    }

    // gram of [3][9] features, /27 true division, symmetric halves bitwise-equal
    #pragma unroll
    for (int c = 0; c < 3; ++c)
        #pragma unroll
        for (int d = c; d < 3; ++d) {
            float g = 0.0f;
            #pragma unroll
            for (int e = 0; e < 9; ++e) g += pix[c][e] * pix[d][e];
            g = g / 27.0f;
            dst[c*3 + d] = g;
            dst[d*3 + c] = g;
        }
}

// ---------------- kernel 2: score + argmin + per-block L1 partial ------------
// One 64-lane wave per (b,n); lanes split m over [0,756) stride 64.
// NO global atomics: 4 wave partials -> LDS -> one plain store per block.
__global__ void __launch_bounds__(256)
score_kernel(const float* __restrict__ ws_ro, float* __restrict__ ws) {
    const float* p1c = ws_ro + P1_OFF;
    const float* p2c = ws_ro + P2CAT_OFF;
    int waveid = threadIdx.x >> 6;
    int lane   = threadIdx.x & 63;
    int wave = blockIdx.x * 4 + waveid;               // 576 blocks * 4 waves = 2304
    int b = wave / 576, n = wave - b*576;
    const float* a1 = p1c + (b*576 + n)*9;
    const float* a2 = p2c + (b*756 + n)*9;            // p2 row n is p2cat row n
    float v1[9], v2[9];
    #pragma unroll
    for (int d = 0; d < 9; ++d) { v1[d] = a1[d]; v2[d] = a2[d]; }
    float n1 = 0.0f, n2 = 0.0f;
    #pragma unroll
    for (int d = 0; d < 9; ++d) { n1 += v1[d]*v1[d]; n2 += v2[d]*v2[d]; }
    float best = 3.402823466e+38f;
    int bidx = 0x7fffffff;
    const float* qb = p2c + b*756*9;
    for (int m = lane; m < 756; m += 64) {
        const float* q = qb + m*9;
        float nq = 0.0f, d1 = 0.0f, d2 = 0.0f;
        #pragma unroll
        for (int d = 0; d < 9; ++d) {
            float qv = q[d];
            nq += qv*qv; d1 += v1[d]*qv; d2 += v2[d]*qv;
        }
        float s = fmaxf((n1 + nq) - 2.0f*d1, 0.0f) + fmaxf((n2 + nq) - 2.0f*d2, 0.0f);
        if (s < best) { best = s; bidx = m; }         // strict <: first-min within lane
    }
    // cross-lane argmin, ties -> smaller index (jnp.argmin first-occurrence)
    #pragma unroll
    for (int off = 32; off > 0; off >>= 1) {
        float ob = __shfl_down(best, off);
        int   oi = __shfl_down(bidx, off);
        if (ob < best || (ob == best && oi < bidx)) { best = ob; bidx = oi; }
    }
    __shared__ float wpart[4];
    if (lane == 0) {
        const float* q = qb + bidx*9;
        float s = 0.0f;
        #pragma unroll
        for (int d = 0; d < 9; ++d) s += fabsf(v1[d] - q[d]);
        wpart[waveid] = s;
    }
    __syncthreads();
    if (threadIdx.x == 0)
        ws[PART_OFF + blockIdx.x] = (wpart[0] + wpart[1]) + (wpart[2] + wpart[3]);
}

// ---------------- kernel 3: finalize (tree-sum 576 partials) -----------------
__global__ void __launch_bounds__(256)
finalize_kernel(const float* __restrict__ ws, float* __restrict__ out) {
    int t = threadIdx.x;
    float s = ws[PART_OFF + t] + ws[PART_OFF + t + 256];
    if (t < 64) s += ws[PART_OFF + t + 512];
    #pragma unroll
    for (int off = 32; off > 0; off >>= 1) s += __shfl_down(s, off);
    __shared__ float wsum[4];
    if ((t & 63) == 0) wsum[t >> 6] = s;
    __syncthreads();
    if (t == 0)
        out[0] = ((wsum[0] + wsum[1]) + (wsum[2] + wsum[3])) / 20736.0f;
}

extern "C" void kernel_launch(void* const* d_in, const int* in_sizes, int n_in,
                              void* d_out, int out_size, void* d_ws, size_t ws_size,
                              hipStream_t stream) {
    const float* x  = (const float*)d_in[0];
    const float* gt = (const float*)d_in[1];
    float* ws  = (float*)d_ws;
    float* out = (float*)d_out;

    fused_gram_kernel<<<21, 256, 0, stream>>>(x, gt, ws);  // 5328 work items
    score_kernel<<<576, 256, 0, stream>>>(ws, ws);         // 2304 waves
    finalize_kernel<<<1, 256, 0, stream>>>(ws, out);
}

// Round 3
// 85.896 us; speedup vs baseline: 1.1398x; 1.0759x over previous
//
#include <hip/hip_runtime.h>

// ---------------- workspace layout (floats) ----------------
#define PART_OFF  0                     // 576 per-block partial L1 sums

__device__ __forceinline__ int clip71(int v) { return v < 0 ? 0 : (v > 71 ? 71 : v); }

#define W0 (-0.09375f)
#define W1 (0.59375f)
#define W2 (0.59375f)
#define W3 (-0.09375f)

// ---------------- fused kernel: downsample + grams (LDS) + score + argmin ----
// 576 blocks of 256. Block bi: b = bi/144, handles n in [ (bi%144)*4, +4 ), one
// wave per n. Phase 1: 256 threads compute all 756 q-grams of batch b into LDS
// (bitwise-identical op sequences to the reference: direct grams of gt, grams
// of inline bicubic f=2 / f=4 downsamples, H-pass-then-W-pass, /27.0f).
// Phase 2: each wave computes its p1 row from x, sweeps 756 candidates from
// LDS (stride-9 -> 2-way bank aliasing only, free), argmin w/ first-index
// tie-break, L1 partial -> one plain store per block. No global atomics.
__global__ void __launch_bounds__(256)
fused_kernel(const float* __restrict__ x, const float* __restrict__ gt,
             float* __restrict__ ws) {
    __shared__ float qsm[756 * 9];      // 27216 B
    __shared__ float wpart[4];

    const int bi = blockIdx.x;
    const int b  = bi / 144;
    const int group = bi - b * 144;     // n-block within batch: n = group*4 + wave

    // ---------------- phase 1: all 756 q-grams of batch b into LDS ----------
    for (int g = threadIdx.x; g < 756; g += 256) {
        float pix[3][9];
        if (g < 576) {
            // direct 3x3 patch of gt (72x72)
            int ph = g / 24, pw = g - ph * 24;
            const float* base = gt + b * 15552 + (3 * ph) * 72 + 3 * pw;
            #pragma unroll
            for (int c = 0; c < 3; ++c)
                #pragma unroll
                for (int i = 0; i < 3; ++i)
                    #pragma unroll
                    for (int j = 0; j < 3; ++j)
                        pix[c][i * 3 + j] = base[c * 5184 + i * 72 + j];
        } else if (g < 720) {
            // f=2 bicubic downsample computed inline (8x8 source window)
            int n2 = g - 576;
            int ph = n2 / 12, pw = n2 - ph * 12;
            int rt[8], ct[8];
            #pragma unroll
            for (int k = 0; k < 8; ++k) {
                rt[k] = clip71(6 * ph - 1 + k);
                ct[k] = clip71(6 * pw - 1 + k);
            }
            #pragma unroll
            for (int c = 0; c < 3; ++c) {
                const float* src = gt + (b * 3 + c) * 5184;
                float R[8][8];
                #pragma unroll
                for (int i = 0; i < 8; ++i)
                    #pragma unroll
                    for (int j = 0; j < 8; ++j)
                        R[i][j] = src[rt[i] * 72 + ct[j]];
                #pragma unroll
                for (int i = 0; i < 3; ++i)
                    #pragma unroll
                    for (int j = 0; j < 3; ++j) {
                        float t0, t1, t2, t3, o;
                        t0  = W0 * R[2*i][2*j];   t0 += W1 * R[2*i+1][2*j];   t0 += W2 * R[2*i+2][2*j];   t0 += W3 * R[2*i+3][2*j];
                        t1  = W0 * R[2*i][2*j+1]; t1 += W1 * R[2*i+1][2*j+1]; t1 += W2 * R[2*i+2][2*j+1]; t1 += W3 * R[2*i+3][2*j+1];
                        t2  = W0 * R[2*i][2*j+2]; t2 += W1 * R[2*i+1][2*j+2]; t2 += W2 * R[2*i+2][2*j+2]; t2 += W3 * R[2*i+3][2*j+2];
                        t3  = W0 * R[2*i][2*j+3]; t3 += W1 * R[2*i+1][2*j+3]; t3 += W2 * R[2*i+2][2*j+3]; t3 += W3 * R[2*i+3][2*j+3];
                        o  = W0 * t0; o += W1 * t1; o += W2 * t2; o += W3 * t3;
                        pix[c][i * 3 + j] = o;
                    }
            }
        } else {
            // f=4 bicubic downsample inline (taps never clip: 12*ph+4i+3 <= 71)
            int n2 = g - 720;
            int ph = n2 / 6, pw = n2 - ph * 6;
            #pragma unroll
            for (int c = 0; c < 3; ++c) {
                const float* src = gt + (b * 3 + c) * 5184;
                #pragma unroll
                for (int i = 0; i < 3; ++i)
                    #pragma unroll
                    for (int j = 0; j < 3; ++j) {
                        const float* p = src + (12 * ph + 4 * i) * 72 + (12 * pw + 4 * j);
                        float t0, t1, t2, t3, o;
                        t0  = W0 * p[0]; t0 += W1 * p[72]; t0 += W2 * p[144]; t0 += W3 * p[216];
                        t1  = W0 * p[1]; t1 += W1 * p[73]; t1 += W2 * p[145]; t1 += W3 * p[217];
                        t2  = W0 * p[2]; t2 += W1 * p[74]; t2 += W2 * p[146]; t2 += W3 * p[218];
                        t3  = W0 * p[3]; t3 += W1 * p[75]; t3 += W2 * p[147]; t3 += W3 * p[219];
                        o  = W0 * t0; o += W1 * t1; o += W2 * t2; o += W3 * t3;
                        pix[c][i * 3 + j] = o;
                    }
            }
        }
        // gram /27 true division, symmetric halves bitwise-equal
        #pragma unroll
        for (int c = 0; c < 3; ++c)
            #pragma unroll
            for (int d = c; d < 3; ++d) {
                float s = 0.0f;
                #pragma unroll
                for (int e = 0; e < 9; ++e) s += pix[c][e] * pix[d][e];
                s = s / 27.0f;
                qsm[g * 9 + c * 3 + d] = s;
                qsm[g * 9 + d * 3 + c] = s;
            }
    }
    __syncthreads();

    // ---------------- phase 2: score sweep, one wave per n ------------------
    const int waveid = threadIdx.x >> 6;
    const int lane   = threadIdx.x & 63;
    const int n = group * 4 + waveid;

    // p1 row n: direct gram of x patch n (identical op order to reference)
    float v1[9];
    {
        int ph = n / 24, pw = n - ph * 24;
        const float* base = x + b * 15552 + (3 * ph) * 72 + 3 * pw;
        float pix[3][9];
        #pragma unroll
        for (int c = 0; c < 3; ++c)
            #pragma unroll
            for (int i = 0; i < 3; ++i)
                #pragma unroll
                for (int j = 0; j < 3; ++j)
                    pix[c][i * 3 + j] = base[c * 5184 + i * 72 + j];
        #pragma unroll
        for (int c = 0; c < 3; ++c)
            #pragma unroll
            for (int d = c; d < 3; ++d) {
                float s = 0.0f;
                #pragma unroll
                for (int e = 0; e < 9; ++e) s += pix[c][e] * pix[d][e];
                s = s / 27.0f;
                v1[c * 3 + d] = s;
                v1[d * 3 + c] = s;
            }
    }
    float v2[9];
    #pragma unroll
    for (int d = 0; d < 9; ++d) v2[d] = qsm[n * 9 + d];   // p2 row n == q row n
    float n1 = 0.0f, n2 = 0.0f;
    #pragma unroll
    for (int d = 0; d < 9; ++d) { n1 += v1[d] * v1[d]; n2 += v2[d] * v2[d]; }

    float best = 3.402823466e+38f;
    int bidx = 0x7fffffff;
    for (int m = lane; m < 756; m += 64) {
        const float* q = qsm + m * 9;
        float nq = 0.0f, d1 = 0.0f, d2 = 0.0f;
        #pragma unroll
        for (int d = 0; d < 9; ++d) {
            float qv = q[d];
            nq += qv * qv; d1 += v1[d] * qv; d2 += v2[d] * qv;
        }
        float s = fmaxf((n1 + nq) - 2.0f * d1, 0.0f) + fmaxf((n2 + nq) - 2.0f * d2, 0.0f);
        if (s < best) { best = s; bidx = m; }       // strict <: first-min within lane
    }
    // cross-lane argmin, ties -> smaller index (jnp.argmin first-occurrence)
    #pragma unroll
    for (int off = 32; off > 0; off >>= 1) {
        float ob = __shfl_down(best, off);
        int   oi = __shfl_down(bidx, off);
        if (ob < best || (ob == best && oi < bidx)) { best = ob; bidx = oi; }
    }
    if (lane == 0) {
        const float* q = qsm + bidx * 9;
        float s = 0.0f;
        #pragma unroll
        for (int d = 0; d < 9; ++d) s += fabsf(v1[d] - q[d]);
        wpart[waveid] = s;
    }
    __syncthreads();
    if (threadIdx.x == 0)
        ws[PART_OFF + blockIdx.x] = (wpart[0] + wpart[1]) + (wpart[2] + wpart[3]);
}

// ---------------- finalize: tree-sum 576 partials ----------------------------
__global__ void __launch_bounds__(256)
finalize_kernel(const float* __restrict__ ws, float* __restrict__ out) {
    int t = threadIdx.x;
    float s = ws[PART_OFF + t] + ws[PART_OFF + t + 256];
    if (t < 64) s += ws[PART_OFF + t + 512];
    #pragma unroll
    for (int off = 32; off > 0; off >>= 1) s += __shfl_down(s, off);
    __shared__ float wsum[4];
    if ((t & 63) == 0) wsum[t >> 6] = s;
    __syncthreads();
    if (t == 0)
        out[0] = ((wsum[0] + wsum[1]) + (wsum[2] + wsum[3])) / 20736.0f;
}

extern "C" void kernel_launch(void* const* d_in, const int* in_sizes, int n_in,
                              void* d_out, int out_size, void* d_ws, size_t ws_size,
                              hipStream_t stream) {
    const float* x  = (const float*)d_in[0];
    const float* gt = (const float*)d_in[1];
    float* ws  = (float*)d_ws;
    float* out = (float*)d_out;

    fused_kernel<<<576, 256, 0, stream>>>(x, gt, ws);
    finalize_kernel<<<1, 256, 0, stream>>>(ws, out);
}

// Round 4
// 73.654 us; speedup vs baseline: 1.3292x; 1.1662x over previous
//
#include <hip/hip_runtime.h>

// ---------------- workspace layout (floats) ----------------
#define PART_OFF  0                     // 144 per-block partial L1 sums

__device__ __forceinline__ int clip71(int v) { return v < 0 ? 0 : (v > 71 ? 71 : v); }

#define W0 (-0.09375f)
#define W1 (0.59375f)
#define W2 (0.59375f)
#define W3 (-0.09375f)

// ---------------- fused kernel: downsample + grams (LDS) + score + argmin ----
// 144 blocks x 1024 threads (16 waves). Block bi: b = bi/36, handles n in
// [ (bi%36)*16, +16 ), one n per wave. 144 blocks <= 256 CUs -> all blocks
// fully parallel, phase-1 redundancy cut 4x vs the 576-block version.
// Phase 1: 1024 threads compute all 756 q-grams of batch b into LDS in ONE
// g-iteration (bitwise-identical fp sequences to the reference: direct grams
// of gt, grams of inline bicubic f=2 / f=4 downsamples, H-pass then W-pass,
// sequential-k accumulation, /27.0f true division).
// Phase 2: each wave computes its p1 row from x, sweeps 756 candidates from
// LDS (stride-9 -> 2-way bank aliasing, free), argmin w/ first-index
// tie-break, L1 partial -> one plain store per block. No global atomics.
__global__ void __launch_bounds__(1024)
fused_kernel(const float* __restrict__ x, const float* __restrict__ gt,
             float* __restrict__ ws) {
    __shared__ float qsm[756 * 9];      // 27216 B
    __shared__ float wpart[16];

    const int bi = blockIdx.x;
    const int b  = bi / 36;
    const int group = bi - b * 36;      // n-block within batch: n = group*16 + wave

    // ---------------- phase 1: all 756 q-grams of batch b into LDS ----------
    {
        const int g = threadIdx.x;      // single iteration: 756 <= 1024
        float pix[3][9];
        bool active = (g < 756);
        if (g < 576) {
            // direct 3x3 patch of gt (72x72)
            int ph = g / 24, pw = g - ph * 24;
            const float* base = gt + b * 15552 + (3 * ph) * 72 + 3 * pw;
            #pragma unroll
            for (int c = 0; c < 3; ++c)
                #pragma unroll
                for (int i = 0; i < 3; ++i)
                    #pragma unroll
                    for (int j = 0; j < 3; ++j)
                        pix[c][i * 3 + j] = base[c * 5184 + i * 72 + j];
        } else if (g < 720) {
            // f=2 bicubic downsample inline. H-pass (axis=2) into hbuf[3][8],
            // then W-pass (axis=3) -- reference order, sequential k.
            int n2 = g - 576;
            int ph = n2 / 12, pw = n2 - ph * 12;
            int rt[8], ct[8];
            #pragma unroll
            for (int k = 0; k < 8; ++k) {
                rt[k] = clip71(6 * ph - 1 + k) * 72;
                ct[k] = clip71(6 * pw - 1 + k);
            }
            #pragma unroll
            for (int c = 0; c < 3; ++c) {
                const float* src = gt + (b * 3 + c) * 5184;
                float hbuf[3][8];
                #pragma unroll
                for (int i = 0; i < 3; ++i)
                    #pragma unroll
                    for (int jj = 0; jj < 8; ++jj) {
                        float h;
                        h  = W0 * src[rt[2*i]     + ct[jj]];
                        h += W1 * src[rt[2*i + 1] + ct[jj]];
                        h += W2 * src[rt[2*i + 2] + ct[jj]];
                        h += W3 * src[rt[2*i + 3] + ct[jj]];
                        hbuf[i][jj] = h;
                    }
                #pragma unroll
                for (int i = 0; i < 3; ++i)
                    #pragma unroll
                    for (int j = 0; j < 3; ++j) {
                        float o;
                        o  = W0 * hbuf[i][2*j];
                        o += W1 * hbuf[i][2*j + 1];
                        o += W2 * hbuf[i][2*j + 2];
                        o += W3 * hbuf[i][2*j + 3];
                        pix[c][i * 3 + j] = o;
                    }
            }
        } else if (g < 756) {
            // f=4 bicubic downsample inline (taps never clip: 12*ph+4i+3 <= 71)
            int n2 = g - 720;
            int ph = n2 / 6, pw = n2 - ph * 6;
            #pragma unroll
            for (int c = 0; c < 3; ++c) {
                const float* src = gt + (b * 3 + c) * 5184;
                #pragma unroll
                for (int i = 0; i < 3; ++i)
                    #pragma unroll
                    for (int j = 0; j < 3; ++j) {
                        const float* p = src + (12 * ph + 4 * i) * 72 + (12 * pw + 4 * j);
                        float t0, t1, t2, t3, o;
                        t0  = W0 * p[0]; t0 += W1 * p[72]; t0 += W2 * p[144]; t0 += W3 * p[216];
                        t1  = W0 * p[1]; t1 += W1 * p[73]; t1 += W2 * p[145]; t1 += W3 * p[217];
                        t2  = W0 * p[2]; t2 += W1 * p[74]; t2 += W2 * p[146]; t2 += W3 * p[218];
                        t3  = W0 * p[3]; t3 += W1 * p[75]; t3 += W2 * p[147]; t3 += W3 * p[219];
                        o  = W0 * t0; o += W1 * t1; o += W2 * t2; o += W3 * t3;
                        pix[c][i * 3 + j] = o;
                    }
            }
        }
        if (active) {
            // gram /27 true division, symmetric halves bitwise-equal
            #pragma unroll
            for (int c = 0; c < 3; ++c)
                #pragma unroll
                for (int d = c; d < 3; ++d) {
                    float s = 0.0f;
                    #pragma unroll
                    for (int e = 0; e < 9; ++e) s += pix[c][e] * pix[d][e];
                    s = s / 27.0f;
                    qsm[g * 9 + c * 3 + d] = s;
                    qsm[g * 9 + d * 3 + c] = s;
                }
        }
    }
    __syncthreads();

    // ---------------- phase 2: score sweep, one wave per n ------------------
    const int waveid = threadIdx.x >> 6;
    const int lane   = threadIdx.x & 63;
    const int n = group * 16 + waveid;

    // p1 row n: direct gram of x patch n (identical op order to reference)
    float v1[9];
    {
        int ph = n / 24, pw = n - ph * 24;
        const float* base = x + b * 15552 + (3 * ph) * 72 + 3 * pw;
        float pix[3][9];
        #pragma unroll
        for (int c = 0; c < 3; ++c)
            #pragma unroll
            for (int i = 0; i < 3; ++i)
                #pragma unroll
                for (int j = 0; j < 3; ++j)
                    pix[c][i * 3 + j] = base[c * 5184 + i * 72 + j];
        #pragma unroll
        for (int c = 0; c < 3; ++c)
            #pragma unroll
            for (int d = c; d < 3; ++d) {
                float s = 0.0f;
                #pragma unroll
                for (int e = 0; e < 9; ++e) s += pix[c][e] * pix[d][e];
                s = s / 27.0f;
                v1[c * 3 + d] = s;
                v1[d * 3 + c] = s;
            }
    }
    float v2[9];
    #pragma unroll
    for (int d = 0; d < 9; ++d) v2[d] = qsm[n * 9 + d];   // p2 row n == q row n
    float n1 = 0.0f, n2 = 0.0f;
    #pragma unroll
    for (int d = 0; d < 9; ++d) { n1 += v1[d] * v1[d]; n2 += v2[d] * v2[d]; }

    float best = 3.402823466e+38f;
    int bidx = 0x7fffffff;
    for (int m = lane; m < 756; m += 64) {
        const float* q = qsm + m * 9;
        float nq = 0.0f, d1 = 0.0f, d2 = 0.0f;
        #pragma unroll
        for (int d = 0; d < 9; ++d) {
            float qv = q[d];
            nq += qv * qv; d1 += v1[d] * qv; d2 += v2[d] * qv;
        }
        float s = fmaxf((n1 + nq) - 2.0f * d1, 0.0f) + fmaxf((n2 + nq) - 2.0f * d2, 0.0f);
        if (s < best) { best = s; bidx = m; }       // strict <: first-min within lane
    }
    // cross-lane argmin, ties -> smaller index (jnp.argmin first-occurrence)
    #pragma unroll
    for (int off = 32; off > 0; off >>= 1) {
        float ob = __shfl_down(best, off);
        int   oi = __shfl_down(bidx, off);
        if (ob < best || (ob == best && oi < bidx)) { best = ob; bidx = oi; }
    }
    if (lane == 0) {
        const float* q = qsm + bidx * 9;
        float s = 0.0f;
        #pragma unroll
        for (int d = 0; d < 9; ++d) s += fabsf(v1[d] - q[d]);
        wpart[waveid] = s;
    }
    __syncthreads();
    if (threadIdx.x == 0) {
        float s = 0.0f;
        #pragma unroll
        for (int w = 0; w < 16; ++w) s += wpart[w];
        ws[PART_OFF + blockIdx.x] = s;
    }
}

// ---------------- finalize: single wave sums 144 partials --------------------
__global__ void __launch_bounds__(64)
finalize_kernel(const float* __restrict__ ws, float* __restrict__ out) {
    int t = threadIdx.x;
    float s = ws[PART_OFF + t] + ws[PART_OFF + t + 64];
    if (t < 16) s += ws[PART_OFF + t + 128];
    #pragma unroll
    for (int off = 32; off > 0; off >>= 1) s += __shfl_down(s, off);
    if (t == 0) out[0] = s / 20736.0f;
}

extern "C" void kernel_launch(void* const* d_in, const int* in_sizes, int n_in,
                              void* d_out, int out_size, void* d_ws, size_t ws_size,
                              hipStream_t stream) {
    const float* x  = (const float*)d_in[0];
    const float* gt = (const float*)d_in[1];
    float* ws  = (float*)d_ws;
    float* out = (float*)d_out;

    fused_kernel<<<144, 1024, 0, stream>>>(x, gt, ws);
    finalize_kernel<<<1, 64, 0, stream>>>(ws, out);
}

// Round 5
// 71.816 us; speedup vs baseline: 1.3632x; 1.0256x over previous
//
#include <hip/hip_runtime.h>

// ---------------- workspace layout (floats) ----------------
#define PART_OFF  0                     // 144 per-block partial L1 sums

__device__ __forceinline__ int clip71(int v) { return v < 0 ? 0 : (v > 71 ? 71 : v); }

#define W0 (-0.09375f)
#define W1 (0.59375f)
#define W2 (0.59375f)
#define W3 (-0.09375f)

// ---------------- fused kernel --------------------------------------------
// 144 blocks x 1024 threads (16 waves). Block bi: b = bi/36, handles n in
// [ (bi%36)*16, +16 ), one n per wave.
// P0: all 1024 threads compute the bicubic-downsampled images of batch b
//     per-PIXEL (gt2: 3x36x36, gt4: 3x18x18) into LDS. This spreads the
//     expensive scattered tap-gathers across all 16 waves instead of
//     serializing 432 loads in one wave (round-4 critical path).
//     Per-pixel fp order identical to reference: H-pass (sequential k),
//     then W-pass (sequential k).
// P1: thread g<576: p2 gram from gt AND p1 gram from x (both -> LDS);
//     g in [576,756): gram of 3x3 patch read from gt2s/gt4s (27 LDS reads).
//     Gram: sequential e, /27.0f true division, symmetric halves bitwise-eq.
// P2: one wave per n sweeps 756 candidates from LDS, argmin w/ first-index
//     tie-break, L1 partial -> one plain store per block. No global atomics.
__global__ void __launch_bounds__(1024)
fused_kernel(const float* __restrict__ x, const float* __restrict__ gt,
             float* __restrict__ ws) {
    __shared__ float gt2s[3 * 36 * 36];   // 15552 B
    __shared__ float gt4s[3 * 18 * 18];   //  3888 B
    __shared__ float qsm[756 * 9];        // 27216 B
    __shared__ float p1sm[576 * 9];       // 20736 B
    __shared__ float wpart[16];

    const int bi = blockIdx.x;
    const int b  = bi / 36;
    const int group = bi - b * 36;        // n = group*16 + waveid

    // ---------------- P0: downsampled pixels into LDS -----------------------
    for (int p = threadIdx.x; p < 3888 + 972; p += 1024) {
        if (p < 3888) {
            // gt2 pixel: c = p/1296, oh = (p%1296)/36, ow = p%36
            int c = p / 1296; int r = p - c * 1296; int oh = r / 36; int ow = r - oh * 36;
            const float* src = gt + (b * 3 + c) * 5184;
            int r0 = clip71(2*oh - 1) * 72, r1 = (2*oh) * 72, r2 = (2*oh + 1) * 72, r3 = clip71(2*oh + 2) * 72;
            int c0 = clip71(2*ow - 1),      c1 = 2*ow,        c2 = 2*ow + 1,        c3 = clip71(2*ow + 2);
            float t0, t1, t2, t3, o;
            t0  = W0 * src[r0 + c0]; t0 += W1 * src[r1 + c0]; t0 += W2 * src[r2 + c0]; t0 += W3 * src[r3 + c0];
            t1  = W0 * src[r0 + c1]; t1 += W1 * src[r1 + c1]; t1 += W2 * src[r2 + c1]; t1 += W3 * src[r3 + c1];
            t2  = W0 * src[r0 + c2]; t2 += W1 * src[r1 + c2]; t2 += W2 * src[r2 + c2]; t2 += W3 * src[r3 + c2];
            t3  = W0 * src[r0 + c3]; t3 += W1 * src[r1 + c3]; t3 += W2 * src[r2 + c3]; t3 += W3 * src[r3 + c3];
            o  = W0 * t0; o += W1 * t1; o += W2 * t2; o += W3 * t3;
            gt2s[p] = o;
        } else {
            // gt4 pixel: taps never clip (4*17+3 = 71)
            int u = p - 3888;
            int c = u / 324; int r = u - c * 324; int oh = r / 18; int ow = r - oh * 18;
            const float* src = gt + (b * 3 + c) * 5184;
            const float* q = src + (4 * oh) * 72 + 4 * ow;
            float t0, t1, t2, t3, o;
            t0  = W0 * q[0]; t0 += W1 * q[72]; t0 += W2 * q[144]; t0 += W3 * q[216];
            t1  = W0 * q[1]; t1 += W1 * q[73]; t1 += W2 * q[145]; t1 += W3 * q[217];
            t2  = W0 * q[2]; t2 += W1 * q[74]; t2 += W2 * q[146]; t2 += W3 * q[218];
            t3  = W0 * q[3]; t3 += W1 * q[75]; t3 += W2 * q[147]; t3 += W3 * q[219];
            o  = W0 * t0; o += W1 * t1; o += W2 * t2; o += W3 * t3;
            gt4s[u] = o;
        }
    }
    __syncthreads();

    // ---------------- P1: all grams into LDS --------------------------------
    {
        const int g = threadIdx.x;
        if (g < 576) {
            int ph = g / 24, pw = g - ph * 24;
            // p2 gram from gt
            {
                const float* base = gt + b * 15552 + (3 * ph) * 72 + 3 * pw;
                float pix[3][9];
                #pragma unroll
                for (int c = 0; c < 3; ++c)
                    #pragma unroll
                    for (int i = 0; i < 3; ++i)
                        #pragma unroll
                        for (int j = 0; j < 3; ++j)
                            pix[c][i * 3 + j] = base[c * 5184 + i * 72 + j];
                #pragma unroll
                for (int c = 0; c < 3; ++c)
                    #pragma unroll
                    for (int d = c; d < 3; ++d) {
                        float s = 0.0f;
                        #pragma unroll
                        for (int e = 0; e < 9; ++e) s += pix[c][e] * pix[d][e];
                        s = s / 27.0f;
                        qsm[g * 9 + c * 3 + d] = s;
                        qsm[g * 9 + d * 3 + c] = s;
                    }
            }
            // p1 gram from x
            {
                const float* base = x + b * 15552 + (3 * ph) * 72 + 3 * pw;
                float pix[3][9];
                #pragma unroll
                for (int c = 0; c < 3; ++c)
                    #pragma unroll
                    for (int i = 0; i < 3; ++i)
                        #pragma unroll
                        for (int j = 0; j < 3; ++j)
                            pix[c][i * 3 + j] = base[c * 5184 + i * 72 + j];
                #pragma unroll
                for (int c = 0; c < 3; ++c)
                    #pragma unroll
                    for (int d = c; d < 3; ++d) {
                        float s = 0.0f;
                        #pragma unroll
                        for (int e = 0; e < 9; ++e) s += pix[c][e] * pix[d][e];
                        s = s / 27.0f;
                        p1sm[g * 9 + c * 3 + d] = s;
                        p1sm[g * 9 + d * 3 + c] = s;
                    }
            }
        } else if (g < 756) {
            // gram of 3x3 patch of the LDS-resident downsampled image
            float pix[3][9];
            if (g < 720) {
                int n2 = g - 576;
                int ph = n2 / 12, pw = n2 - ph * 12;
                #pragma unroll
                for (int c = 0; c < 3; ++c)
                    #pragma unroll
                    for (int i = 0; i < 3; ++i)
                        #pragma unroll
                        for (int j = 0; j < 3; ++j)
                            pix[c][i * 3 + j] = gt2s[c * 1296 + (3 * ph + i) * 36 + (3 * pw + j)];
            } else {
                int n2 = g - 720;
                int ph = n2 / 6, pw = n2 - ph * 6;
                #pragma unroll
                for (int c = 0; c < 3; ++c)
                    #pragma unroll
                    for (int i = 0; i < 3; ++i)
                        #pragma unroll
                        for (int j = 0; j < 3; ++j)
                            pix[c][i * 3 + j] = gt4s[c * 324 + (3 * ph + i) * 18 + (3 * pw + j)];
            }
            #pragma unroll
            for (int c = 0; c < 3; ++c)
                #pragma unroll
                for (int d = c; d < 3; ++d) {
                    float s = 0.0f;
                    #pragma unroll
                    for (int e = 0; e < 9; ++e) s += pix[c][e] * pix[d][e];
                    s = s / 27.0f;
                    qsm[g * 9 + c * 3 + d] = s;
                    qsm[g * 9 + d * 3 + c] = s;
                }
        }
    }
    __syncthreads();

    // ---------------- P2: score sweep, one wave per n ------------------------
    const int waveid = threadIdx.x >> 6;
    const int lane   = threadIdx.x & 63;
    const int n = group * 16 + waveid;

    float v1[9], v2[9];
    #pragma unroll
    for (int d = 0; d < 9; ++d) { v1[d] = p1sm[n * 9 + d]; v2[d] = qsm[n * 9 + d]; }
    float n1 = 0.0f, n2 = 0.0f;
    #pragma unroll
    for (int d = 0; d < 9; ++d) { n1 += v1[d] * v1[d]; n2 += v2[d] * v2[d]; }

    float best = 3.402823466e+38f;
    int bidx = 0x7fffffff;
    for (int m = lane; m < 756; m += 64) {
        const float* q = qsm + m * 9;
        float nq = 0.0f, d1 = 0.0f, d2 = 0.0f;
        #pragma unroll
        for (int d = 0; d < 9; ++d) {
            float qv = q[d];
            nq += qv * qv; d1 += v1[d] * qv; d2 += v2[d] * qv;
        }
        float s = fmaxf((n1 + nq) - 2.0f * d1, 0.0f) + fmaxf((n2 + nq) - 2.0f * d2, 0.0f);
        if (s < best) { best = s; bidx = m; }       // strict <: first-min within lane
    }
    // cross-lane argmin, ties -> smaller index (jnp.argmin first-occurrence)
    #pragma unroll
    for (int off = 32; off > 0; off >>= 1) {
        float ob = __shfl_down(best, off);
        int   oi = __shfl_down(bidx, off);
        if (ob < best || (ob == best && oi < bidx)) { best = ob; bidx = oi; }
    }
    if (lane == 0) {
        const float* q = qsm + bidx * 9;
        float s = 0.0f;
        #pragma unroll
        for (int d = 0; d < 9; ++d) s += fabsf(v1[d] - q[d]);
        wpart[waveid] = s;
    }
    __syncthreads();
    if (threadIdx.x == 0) {
        float s = 0.0f;
        #pragma unroll
        for (int w = 0; w < 16; ++w) s += wpart[w];
        ws[PART_OFF + blockIdx.x] = s;
    }
}

// ---------------- finalize: single wave sums 144 partials --------------------
__global__ void __launch_bounds__(64)
finalize_kernel(const float* __restrict__ ws, float* __restrict__ out) {
    int t = threadIdx.x;
    float s = ws[PART_OFF + t] + ws[PART_OFF + t + 64];
    if (t < 16) s += ws[PART_OFF + t + 128];
    #pragma unroll
    for (int off = 32; off > 0; off >>= 1) s += __shfl_down(s, off);
    if (t == 0) out[0] = s / 20736.0f;
}

extern "C" void kernel_launch(void* const* d_in, const int* in_sizes, int n_in,
                              void* d_out, int out_size, void* d_ws, size_t ws_size,
                              hipStream_t stream) {
    const float* x  = (const float*)d_in[0];
    const float* gt = (const float*)d_in[1];
    float* ws  = (float*)d_ws;
    float* out = (float*)d_out;

    fused_kernel<<<144, 1024, 0, stream>>>(x, gt, ws);
    finalize_kernel<<<1, 64, 0, stream>>>(ws, out);
}